// Round 1
// baseline (24.942 us; speedup 1.0000x reference)
//
#include <hip/hip_runtime.h>

#define BATCH   64
#define NPATCH  64
#define NB1     10      // BIN1
#define NBT     16      // BIN_T
#define MOUT    9       // BIN1-1
#define ROWLEN  160     // NBT*NB1
#define ROWPAD  161     // +1 pad: 161 % 32 == 1 -> conflict-free column reads
#define OUTD    5760    // NPATCH*NB1*MOUT
#define EPS2f   0.001f
#define LN2f    0.69314718055994530942f

__global__ __launch_bounds__(576) void until_kernel(
    const float* __restrict__ x,
    const float* __restrict__ bound1,
    const float* __restrict__ bound2,
    float* __restrict__ out)
{
    __shared__ float xs[BATCH][ROWPAD];      // 41.2 KB
    __shared__ float w1s[MOUT][NBT][NBT];    // 9.2 KB
    __shared__ float wfs[MOUT][NBT];         // 0.6 KB

    const int tid = threadIdx.x;
    const int pj  = blockIdx.x;              // 0..639  => (p, j)
    const int p   = pj / NB1;
    const int j   = pj - p * NB1;

    // ---- Phase 1: stage x[:, p*160 .. p*160+159] into LDS (coalesced float4)
    for (int i = tid; i < BATCH * (ROWLEN / 4); i += 576) {
        const int b  = i / (ROWLEN / 4);
        const int c4 = (i - b * (ROWLEN / 4)) * 4;
        const float4 v = *reinterpret_cast<const float4*>(
            x + (size_t)b * (NPATCH * ROWLEN) + (size_t)p * ROWLEN + c4);
        xs[b][c4 + 0] = v.x;
        xs[b][c4 + 1] = v.y;
        xs[b][c4 + 2] = v.z;
        xs[b][c4 + 3] = v.w;
    }

    // ---- Phase 2: batch-independent W1 / Wf tables for this (p,j)
    const int boundBase = pj * MOUT;
    for (int i = tid; i < MOUT * NBT * NBT; i += 576) {   // exactly 4 iters
        const int m = i >> 8;
        const int r = i & 255;
        const int t = r >> 4;
        const int s = r & 15;
        const float b1v = bound1[boundBase + m];
        const float b2v = bound2[boundBase + m];
        const float Ws  = fminf(b1v, b2v);               // W_start
        const float z   = ((float)s - Ws) * ((float)t - EPS2f - (float)s);
        w1s[m][t][s] = __builtin_amdgcn_rcpf(1.0f + __expf(-z));
    }
    if (tid < MOUT * NBT) {
        const int m = tid >> 4;
        const int t = tid & 15;
        const float b1v = bound1[boundBase + m];
        const float b2v = bound2[boundBase + m];
        const float Ws  = fminf(b1v, b2v);
        const float We  = fmaxf(b1v, b2v);               // W_end
        const float z   = ((float)t - Ws) * (We - (float)t);
        wfs[m][t] = __builtin_amdgcn_rcpf(1.0f + __expf(-z));
    }

    __syncthreads();

    // ---- Phase 3: wave = m, lane = batch
    const int m    = tid >> 6;      // 0..8
    const int lane = tid & 63;      // batch index
    const int k    = (m < j) ? m : m + 1;   // kidx[j][m]

    float omx[NBT], xtj[NBT];
    #pragma unroll
    for (int s = 0; s < NBT; ++s) {
        // 2-way bank aliasing only (161 % 32 == 1) -> free
        omx[s] = 1.0f - xs[lane][s * NB1 + k];
        xtj[s] = xs[lane][s * NB1 + j];
    }

    float S = 0.0f;
    #pragma unroll
    for (int t = 0; t < NBT; ++t) {
        const float* wrow = &w1s[m][t][0];   // wave-uniform -> LDS broadcast
        float a0 = 0.f, a1 = 0.f, a2 = 0.f, a3 = 0.f;
        #pragma unroll
        for (int s = 0; s < NBT; s += 4) {
            a0 += __log2f(fmaf(-omx[s + 0], wrow[s + 0], 1.0f));
            a1 += __log2f(fmaf(-omx[s + 1], wrow[s + 1], 1.0f));
            a2 += __log2f(fmaf(-omx[s + 2], wrow[s + 2], 1.0f));
            a3 += __log2f(fmaf(-omx[s + 3], wrow[s + 3], 1.0f));
        }
        const float sumln = ((a0 + a1) + (a2 + a3)) * LN2f;
        const float xl2   = __builtin_amdgcn_rcpf(1.0f - sumln);  // = -1/(-1+sum)
        const float u     = xtj[t] * xl2 * wfs[m][t];
        const float g     = fmaxf(1.0f - u, 1e-37f);   // guard rounding
        S += __log2f(g);
    }
    const float out_v = 1.0f - __builtin_amdgcn_rcpf(1.0f - S * LN2f);
    out[(size_t)lane * OUTD + (size_t)pj * MOUT + m] = out_v;
}

extern "C" void kernel_launch(void* const* d_in, const int* in_sizes, int n_in,
                              void* d_out, int out_size, void* d_ws, size_t ws_size,
                              hipStream_t stream) {
    const float* x  = (const float*)d_in[0];
    const float* b1 = (const float*)d_in[1];
    const float* b2 = (const float*)d_in[2];
    float* out = (float*)d_out;
    until_kernel<<<dim3(NPATCH * NB1), dim3(576), 0, stream>>>(x, b1, b2, out);
}

// Round 2
// 16.907 us; speedup vs baseline: 1.4753x; 1.4753x over previous
//
#include <hip/hip_runtime.h>

#define NPATCH  64
#define NB1     10
#define NBT     16
#define MOUT    9        // NB1-1
#define ROWLEN  160      // NBT*NB1
#define ROWPAD  161      // 161 % 32 == 1 -> conflict-free column gathers
#define OUTD    5760     // NPATCH*NB1*MOUT
#define EPS2f   0.001f
#define LN2f    0.69314718055994530942f

// Block = (pj, batch-half): 288 threads = 9 m-waves' worth (4.5 waves),
// lane group of 32 = batch, wave spans 2 m values (2-addr LDS reads = free).
// Grid = 640*2 = 1280 blocks -> exactly 5 blocks/CU (LDS 31.6 KB, 5*31.6=158<160).
__global__ __launch_bounds__(288) void until_kernel(
    const float* __restrict__ x,
    const float* __restrict__ bound1,
    const float* __restrict__ bound2,
    float* __restrict__ out)
{
    __shared__ float xs[32][ROWPAD];                       // 20.6 KB
    __shared__ __align__(16) float w1s[MOUT][NBT][NBT];    // 9.2 KB
    __shared__ __align__(16) float wfs[MOUT][NBT];         // 576 B
    __shared__ float ob[288];                              // 1.2 KB

    const int tid  = threadIdx.x;
    const int bid  = blockIdx.x;
    const int pj   = bid >> 1;        // 0..639
    const int half = bid & 1;         // batch half
    const int p    = pj / NB1;
    const int j    = pj - p * NB1;

    // ---- stage this half's 32 batch rows of patch p (coalesced float4)
    for (int i = tid; i < 32 * (ROWLEN / 4); i += 288) {
        const int b4 = i / 40;
        const int c4 = (i - b4 * 40) * 4;
        const float4 v = *reinterpret_cast<const float4*>(
            x + (size_t)(half * 32 + b4) * (NPATCH * ROWLEN) + p * ROWLEN + c4);
        xs[b4][c4 + 0] = v.x;
        xs[b4][c4 + 1] = v.y;
        xs[b4][c4 + 2] = v.z;
        xs[b4][c4 + 3] = v.w;
    }

    // ---- batch-independent W1 / Wf tables for this (p,j)   (8 iters exact)
    const int bb = pj * MOUT;
    for (int i = tid; i < MOUT * NBT * NBT; i += 288) {
        const int m = i >> 8;
        const int r = i & 255;
        const int t = r >> 4;
        const int s = r & 15;
        const float b1v = bound1[bb + m];
        const float b2v = bound2[bb + m];
        const float Ws  = fminf(b1v, b2v);                  // W_start
        const float z   = ((float)s - Ws) * ((float)t - EPS2f - (float)s);
        w1s[m][t][s] = __builtin_amdgcn_rcpf(1.0f + __expf(-z));
    }
    if (tid < MOUT * NBT) {
        const int m = tid >> 4;
        const int t = tid & 15;
        const float b1v = bound1[bb + m];
        const float b2v = bound2[bb + m];
        const float Ws  = fminf(b1v, b2v);
        const float We  = fmaxf(b1v, b2v);                  // W_end
        const float z   = ((float)t - Ws) * (We - (float)t);
        wfs[m][t] = __builtin_amdgcn_rcpf(1.0f + __expf(-z));
    }

    __syncthreads();

    // ---- compute: thread = (m, batch-in-half)
    const int m   = tid / 32;         // 0..8
    const int b32 = tid & 31;         // batch within half
    const int k   = (m < j) ? m : m + 1;   // kidx[j][m]

    float omx[NBT], xtj[NBT];
    #pragma unroll
    for (int s = 0; s < NBT; ++s) {   // (lane + const) % 32 -> conflict-free
        omx[s] = 1.0f - xs[b32][s * NB1 + k];
        xtj[s] = xs[b32][s * NB1 + j];
    }

    float wfr[NBT];
    {
        const float4* wf4 = reinterpret_cast<const float4*>(&wfs[m][0]);
        #pragma unroll
        for (int q = 0; q < 4; ++q)
            *reinterpret_cast<float4*>(&wfr[q * 4]) = wf4[q];
    }

    float qacc = 1.0f;
    #pragma unroll
    for (int t = 0; t < NBT; ++t) {
        const float4* w4 = reinterpret_cast<const float4*>(&w1s[m][t][0]);
        float wv[NBT];
        *reinterpret_cast<float4*>(&wv[0])  = w4[0];
        *reinterpret_cast<float4*>(&wv[4])  = w4[1];
        *reinterpret_cast<float4*>(&wv[8])  = w4[2];
        *reinterpret_cast<float4*>(&wv[12]) = w4[3];

        float e[NBT];
        #pragma unroll
        for (int s = 0; s < NBT; ++s)
            e[s] = fmaf(-omx[s], wv[s], 1.0f);      // X1 = 1 - (1-x)*W1

        const float m0 = (e[0]  * e[1])  * (e[2]  * e[3]);
        const float m1 = (e[4]  * e[5])  * (e[6]  * e[7]);
        const float m2 = (e[8]  * e[9])  * (e[10] * e[11]);
        const float m3 = (e[12] * e[13]) * (e[14] * e[15]);
        const float pr = (m0 * m1) * (m2 * m3);     // prod_s X1

        // x_layer2 = 1/(1 - ln P); P=0 -> log2=-inf -> rcp(+inf)=0 (exact limit)
        const float lp2 = __log2f(pr);
        const float xl2 = __builtin_amdgcn_rcpf(fmaf(-LN2f, lp2, 1.0f));
        const float u   = xtj[t] * xl2 * wfr[t];
        qacc *= (1.0f - u);                          // prod_t (1 - x_until*Wf)
    }

    // out = 1 + 1/(S-1), S = ln qacc; qacc=0 -> rcp(-inf)=-0 -> out=1 (limit)
    const float S = LN2f * __log2f(qacc);
    ob[b32 * MOUT + m] = 1.0f + __builtin_amdgcn_rcpf(S - 1.0f);

    __syncthreads();

    // ---- repacked store: consecutive lanes hit consecutive flat indices
    {
        const int bo = tid / MOUT;
        const int mo = tid - bo * MOUT;
        out[(size_t)(half * 32 + bo) * OUTD + bb + mo] = ob[tid];
    }
}

extern "C" void kernel_launch(void* const* d_in, const int* in_sizes, int n_in,
                              void* d_out, int out_size, void* d_ws, size_t ws_size,
                              hipStream_t stream) {
    const float* x  = (const float*)d_in[0];
    const float* b1 = (const float*)d_in[1];
    const float* b2 = (const float*)d_in[2];
    float* out = (float*)d_out;
    until_kernel<<<dim3(NPATCH * NB1 * 2), dim3(288), 0, stream>>>(x, b1, b2, out);
}

// Round 3
// 16.394 us; speedup vs baseline: 1.5214x; 1.0312x over previous
//
#include <hip/hip_runtime.h>

#define NPATCH  64
#define NB1     10
#define NBT     16
#define MOUT    9        // NB1-1
#define ROWLEN  160      // NBT*NB1
#define ROWPAD  161      // 161 % 32 == 1 -> conflict-free column gathers
#define OUTD    5760     // NPATCH*NB1*MOUT
#define EPS2f   0.001f
#define LN2f    0.69314718055994530942f

typedef float f32x2 __attribute__((ext_vector_type(2)));

static __device__ __forceinline__ f32x2 pk_fma(f32x2 a, f32x2 b, f32x2 c) {
    f32x2 d;
    asm("v_pk_fma_f32 %0, %1, %2, %3" : "=v"(d) : "v"(a), "v"(b), "v"(c));
    return d;
}
static __device__ __forceinline__ f32x2 pk_mul(f32x2 a, f32x2 b) {
    f32x2 d;
    asm("v_pk_mul_f32 %0, %1, %2" : "=v"(d) : "v"(a), "v"(b));
    return d;
}

// Block = pj (640 blocks), 576 threads = 9 waves; wave = m, lane = batch.
// W1 row reads are wave-uniform (LDS broadcast). All 640 blocks co-resident:
// LDS 51 KB -> 3 blocks/CU, 27 waves/CU, zero dispatch tail.
__global__ __launch_bounds__(576) void until_kernel(
    const float* __restrict__ x,
    const float* __restrict__ bound1,
    const float* __restrict__ bound2,
    float* __restrict__ out)
{
    __shared__ float xs[64][ROWPAD];                       // 41.2 KB
    __shared__ __align__(16) float w1s[MOUT][NBT][NBT];    // 9.2 KB (reused as ob)
    __shared__ __align__(16) float wfs[MOUT][NBT];         // 576 B

    const int tid = threadIdx.x;
    const int pj  = blockIdx.x;       // 0..639
    const int p   = pj / NB1;
    const int j   = pj - p * NB1;

    // ---- stage all 64 batch rows of patch p (coalesced float4)
    for (int i = tid; i < 64 * (ROWLEN / 4); i += 576) {
        const int b4 = i / 40;
        const int c4 = (i - b4 * 40) * 4;
        const float4 v = *reinterpret_cast<const float4*>(
            x + (size_t)b4 * (NPATCH * ROWLEN) + p * ROWLEN + c4);
        xs[b4][c4 + 0] = v.x;
        xs[b4][c4 + 1] = v.y;
        xs[b4][c4 + 2] = v.z;
        xs[b4][c4 + 3] = v.w;
    }

    // ---- batch-independent W1 / Wf tables for this (p,j)  (exactly 4 iters)
    const int bb = pj * MOUT;
    for (int i = tid; i < MOUT * NBT * NBT; i += 576) {
        const int m = i >> 8;
        const int r = i & 255;
        const int t = r >> 4;
        const int s = r & 15;
        const float b1v = bound1[bb + m];
        const float b2v = bound2[bb + m];
        const float Ws  = fminf(b1v, b2v);                  // W_start
        const float z   = ((float)s - Ws) * ((float)t - EPS2f - (float)s);
        w1s[m][t][s] = __builtin_amdgcn_rcpf(1.0f + __expf(-z));
    }
    if (tid < MOUT * NBT) {
        const int m = tid >> 4;
        const int t = tid & 15;
        const float b1v = bound1[bb + m];
        const float b2v = bound2[bb + m];
        const float Ws  = fminf(b1v, b2v);
        const float We  = fmaxf(b1v, b2v);                  // W_end
        const float z   = ((float)t - Ws) * (We - (float)t);
        wfs[m][t] = __builtin_amdgcn_rcpf(1.0f + __expf(-z));
    }

    __syncthreads();

    // ---- compute: wave = m, lane = batch
    const int m    = tid >> 6;        // 0..8
    const int lane = tid & 63;        // batch
    const int k    = (m < j) ? m : m + 1;   // kidx[j][m]

    // gathers: addr = lane*161 + c, 161%32==1 -> 2 lanes/bank = free
    f32x2 na2[8];                     // -(1 - x_other) pairs
    float xtj[NBT];
    #pragma unroll
    for (int q = 0; q < 8; ++q) {
        f32x2 v;
        v.x = xs[lane][(2 * q + 0) * NB1 + k] - 1.0f;
        v.y = xs[lane][(2 * q + 1) * NB1 + k] - 1.0f;
        na2[q] = v;
    }
    #pragma unroll
    for (int s = 0; s < NBT; ++s)
        xtj[s] = xs[lane][s * NB1 + j];

    float wfr[NBT];
    {
        const float4* wf4 = reinterpret_cast<const float4*>(&wfs[m][0]);
        #pragma unroll
        for (int q = 0; q < 4; ++q)
            *reinterpret_cast<float4*>(&wfr[q * 4]) = wf4[q];
    }

    const f32x2 one2 = {1.0f, 1.0f};
    const float4* w1row = reinterpret_cast<const float4*>(&w1s[m][0][0]);

    float qacc = 1.0f;
    #pragma unroll
    for (int t = 0; t < NBT; ++t) {
        // 4 wave-uniform ds_read_b128 (broadcast)
        const float4 wa = w1row[t * 4 + 0];
        const float4 wb = w1row[t * 4 + 1];
        const float4 wc = w1row[t * 4 + 2];
        const float4 wd = w1row[t * 4 + 3];

        // X1 pairs = 1 - (1-x)*W1  via packed fma (na = x-1)
        const f32x2 e0 = pk_fma(na2[0], f32x2{wa.x, wa.y}, one2);
        const f32x2 e1 = pk_fma(na2[1], f32x2{wa.z, wa.w}, one2);
        const f32x2 e2 = pk_fma(na2[2], f32x2{wb.x, wb.y}, one2);
        const f32x2 e3 = pk_fma(na2[3], f32x2{wb.z, wb.w}, one2);
        const f32x2 e4 = pk_fma(na2[4], f32x2{wc.x, wc.y}, one2);
        const f32x2 e5 = pk_fma(na2[5], f32x2{wc.z, wc.w}, one2);
        const f32x2 e6 = pk_fma(na2[6], f32x2{wd.x, wd.y}, one2);
        const f32x2 e7 = pk_fma(na2[7], f32x2{wd.z, wd.w}, one2);

        // packed product tree: 7 pk_mul + 1 scalar mul
        const f32x2 m0 = pk_mul(e0, e1);
        const f32x2 m1 = pk_mul(e2, e3);
        const f32x2 m2 = pk_mul(e4, e5);
        const f32x2 m3 = pk_mul(e6, e7);
        const f32x2 n0 = pk_mul(m0, m1);
        const f32x2 n1 = pk_mul(m2, m3);
        const f32x2 r  = pk_mul(n0, n1);
        const float pr = r.x * r.y;                 // prod_s X1

        // x_layer2 = 1/(1 - ln P); P=0 -> log2=-inf -> rcp(+inf)=0 (exact limit)
        const float lp2 = __log2f(pr);
        const float xl2 = __builtin_amdgcn_rcpf(fmaf(-LN2f, lp2, 1.0f));
        const float u   = xtj[t] * xl2 * wfr[t];
        qacc = fmaf(-qacc, u, qacc);                // qacc *= (1 - u)
    }

    // out = 1 + 1/(S-1), S = ln qacc; qacc=0 -> rcp(-inf)=-0 -> out=1 (limit)
    const float S     = LN2f * __log2f(qacc);
    const float out_v = 1.0f + __builtin_amdgcn_rcpf(S - 1.0f);

    __syncthreads();                  // w1s no longer needed by any wave
    float* ob = &w1s[0][0][0];        // reuse as 576-float repack buffer
    ob[lane * MOUT + m] = out_v;      // stride 9, gcd(9,32)=1 -> 2-way = free
    __syncthreads();

    // consecutive lanes -> consecutive flat out indices (9-float row chunks)
    {
        const int bo = tid / MOUT;
        const int mo = tid - bo * MOUT;
        out[(size_t)bo * OUTD + bb + mo] = ob[tid];
    }
}

extern "C" void kernel_launch(void* const* d_in, const int* in_sizes, int n_in,
                              void* d_out, int out_size, void* d_ws, size_t ws_size,
                              hipStream_t stream) {
    const float* x  = (const float*)d_in[0];
    const float* b1 = (const float*)d_in[1];
    const float* b2 = (const float*)d_in[2];
    float* out = (float*)d_out;
    until_kernel<<<dim3(NPATCH * NB1), dim3(576), 0, stream>>>(x, b1, b2, out);
}